// Round 1
// baseline (246.528 us; speedup 1.0000x reference)
//
#include <hip/hip_runtime.h>
#include <hip/hip_bf16.h>

#define Bn 64
#define Tn 512
#define Dn 512
#define Hn 128
#define BT (Bn*Tn)

typedef unsigned short u16;
typedef __attribute__((ext_vector_type(8))) short bf16x8;
typedef __attribute__((ext_vector_type(4))) float f32x4;

__device__ __forceinline__ u16 f2bf(float f) {
  union { float f; unsigned u; } v; v.f = f;
  unsigned r = (v.u + 0x7FFFu + ((v.u >> 16) & 1u)) >> 16;
  return (u16)r;
}

// ---------- conversions ----------
__global__ __launch_bounds__(256) void conv_x(const float4* __restrict__ X,
                                              ushort4* __restrict__ Xb) {
  int idx = blockIdx.x * 256 + threadIdx.x;
  float4 v = X[idx];
  ushort4 o; o.x = f2bf(v.x); o.y = f2bf(v.y); o.z = f2bf(v.z); o.w = f2bf(v.w);
  Xb[idx] = o;
}

__global__ __launch_bounds__(256) void conv_w(const float* __restrict__ W,
                                              u16* __restrict__ Wb) {
  int idx = blockIdx.x * 256 + threadIdx.x;
  Wb[idx] = f2bf(W[idx]);
}

// dagT[i*T + k] = dag[k*T + i]  (bf16; entries are exactly 0.0 or 1.0)
__global__ __launch_bounds__(256) void conv_dag(const float* __restrict__ dag,
                                                u16* __restrict__ dagT) {
  int idx = blockIdx.x * 256 + threadIdx.x;
  int i = idx >> 9, k = idx & (Tn - 1);
  dagT[idx] = f2bf(dag[k * Tn + i]);
}

// ---------- stage 1: K,Q,V = swish(X W^T + b) ----------
// grid (BT/64, 3), block 256 (4 waves). wave w -> rows mw..mw+15.
// K -> [B,T,H] row-major; Q,V -> transposed [B,H,T].
__global__ __launch_bounds__(256) void qkv_kernel(
    const u16* __restrict__ Xb, const u16* __restrict__ Wb,
    const float* __restrict__ bk, const float* __restrict__ bq,
    const float* __restrict__ bv,
    u16* __restrict__ Kb, u16* __restrict__ QT, u16* __restrict__ VT) {
  int which = blockIdx.y;                 // 0=K, 1=Q, 2=V
  int wave = threadIdx.x >> 6, lane = threadIdx.x & 63;
  int mw = blockIdx.x * 64 + wave * 16;
  const u16* W = Wb + which * (Hn * Dn);
  const float* bias = (which == 0) ? bk : ((which == 1) ? bq : bv);

  f32x4 acc[8] = {};
  const u16* Arow = Xb + (size_t)(mw + (lane & 15)) * Dn + ((lane >> 4) * 8);
  for (int kk = 0; kk < Dn; kk += 32) {
    bf16x8 a = *(const bf16x8*)(Arow + kk);
#pragma unroll
    for (int f = 0; f < 8; ++f) {
      bf16x8 b = *(const bf16x8*)(W + (size_t)(f * 16 + (lane & 15)) * Dn +
                                  ((lane >> 4) * 8) + kk);
      acc[f] = __builtin_amdgcn_mfma_f32_16x16x32_bf16(a, b, acc[f], 0, 0, 0);
    }
  }
  int col0 = lane & 15, rbase = (lane >> 4) * 4;
#pragma unroll
  for (int f = 0; f < 8; ++f) {
    int n = f * 16 + col0;
    float bs = bias[n];
#pragma unroll
    for (int r = 0; r < 4; ++r) {
      int row = mw + rbase + r;           // global token index [0, BT)
      float x = acc[f][r] + bs;
      float s = x / (1.f + __expf(-x));   // swish
      u16 h = f2bf(s);
      if (which == 0) {
        Kb[(size_t)row * Hn + n] = h;
      } else {
        int b = row >> 9, t = row & (Tn - 1);
        u16* dst = (which == 1) ? QT : VT;
        dst[((size_t)b * Hn + n) * Tn + t] = h;
      }
    }
  }
}

// ---------- stage 2: Q2 = (dagT @ Q) / sqrt(H) ----------
// grid (T/64, B). A = dagT [T,T], B = QT[b] (n=h, k=j contiguous).
__global__ __launch_bounds__(256) void dagq_kernel(
    const u16* __restrict__ dagT, const u16* __restrict__ QT,
    u16* __restrict__ Q2) {
  int b = blockIdx.y;
  int wave = threadIdx.x >> 6, lane = threadIdx.x & 63;
  int mw = blockIdx.x * 64 + wave * 16;
  const u16* Qb = QT + (size_t)b * Hn * Tn;

  f32x4 acc[8] = {};
  const u16* Arow = dagT + (size_t)(mw + (lane & 15)) * Tn + ((lane >> 4) * 8);
  for (int kk = 0; kk < Tn; kk += 32) {
    bf16x8 a = *(const bf16x8*)(Arow + kk);
#pragma unroll
    for (int f = 0; f < 8; ++f) {
      bf16x8 bb = *(const bf16x8*)(Qb + (size_t)(f * 16 + (lane & 15)) * Tn +
                                   ((lane >> 4) * 8) + kk);
      acc[f] = __builtin_amdgcn_mfma_f32_16x16x32_bf16(a, bb, acc[f], 0, 0, 0);
    }
  }
  const float scale = 0.08838834764831845f;  // 1/sqrt(128)
  int col0 = lane & 15, rbase = (lane >> 4) * 4;
#pragma unroll
  for (int f = 0; f < 8; ++f) {
    int h = f * 16 + col0;
#pragma unroll
    for (int r = 0; r < 4; ++r) {
      int i = mw + rbase + r;
      Q2[((size_t)b * Tn + i) * Hn + h] = f2bf(acc[f][r] * scale);
    }
  }
}

// ---------- stage 3: S2 = Q2 K^T, mask by dagT, row softmax, P2 = probs + dagT ----------
// grid (T/16, B), block 256. Block owns 16 full rows (512 cols); wave w -> cols [w*128, w*128+128).
__global__ __launch_bounds__(256) void attn_kernel(
    const u16* __restrict__ Q2, const u16* __restrict__ Kb,
    const u16* __restrict__ dagT, u16* __restrict__ P2) {
  int b = blockIdx.y;
  int m0 = blockIdx.x * 16;
  int wave = threadIdx.x >> 6, lane = threadIdx.x & 63;
  int n0w = wave * 128;
  __shared__ float red_max[16][4];
  __shared__ float red_sum[16][4];

  f32x4 acc[8] = {};
  const u16* Arow = Q2 + ((size_t)b * Tn + m0 + (lane & 15)) * Hn + ((lane >> 4) * 8);
  const u16* Kbb = Kb + (size_t)b * Tn * Hn;
  for (int kk = 0; kk < Hn; kk += 32) {
    bf16x8 a = *(const bf16x8*)(Arow + kk);
#pragma unroll
    for (int f = 0; f < 8; ++f) {
      bf16x8 bb = *(const bf16x8*)(Kbb + (size_t)(n0w + f * 16 + (lane & 15)) * Hn +
                                   ((lane >> 4) * 8) + kk);
      acc[f] = __builtin_amdgcn_mfma_f32_16x16x32_bf16(a, bb, acc[f], 0, 0, 0);
    }
  }

  int col0 = lane & 15, rbase = (lane >> 4) * 4;
  float vals[8][4];
  float rmax[4] = {-INFINITY, -INFINITY, -INFINITY, -INFINITY};
#pragma unroll
  for (int f = 0; f < 8; ++f) {
#pragma unroll
    for (int r = 0; r < 4; ++r) {
      int i = m0 + rbase + r;
      int k = n0w + f * 16 + col0;
      bool mz = dagT[(size_t)i * Tn + k] != 0;
      float v = mz ? acc[f][r] : -INFINITY;
      vals[f][r] = v;
      rmax[r] = fmaxf(rmax[r], v);
    }
  }
#pragma unroll
  for (int m = 1; m < 16; m <<= 1)
#pragma unroll
    for (int r = 0; r < 4; ++r) rmax[r] = fmaxf(rmax[r], __shfl_xor(rmax[r], m, 64));
  if ((lane & 15) == 0)
#pragma unroll
    for (int r = 0; r < 4; ++r) red_max[rbase + r][wave] = rmax[r];
  __syncthreads();
  float rowmax[4];
#pragma unroll
  for (int r = 0; r < 4; ++r) {
    float m = fmaxf(fmaxf(red_max[rbase + r][0], red_max[rbase + r][1]),
                    fmaxf(red_max[rbase + r][2], red_max[rbase + r][3]));
    rowmax[r] = (m == -INFINITY) ? 0.f : m;
  }

  float rsum[4] = {0.f, 0.f, 0.f, 0.f};
#pragma unroll
  for (int f = 0; f < 8; ++f) {
#pragma unroll
    for (int r = 0; r < 4; ++r) {
      float e = (vals[f][r] == -INFINITY) ? 0.f : __expf(vals[f][r] - rowmax[r]);
      vals[f][r] = e;                    // reuse storage for exp values
      rsum[r] += e;
    }
  }
#pragma unroll
  for (int m = 1; m < 16; m <<= 1)
#pragma unroll
    for (int r = 0; r < 4; ++r) rsum[r] += __shfl_xor(rsum[r], m, 64);
  if ((lane & 15) == 0)
#pragma unroll
    for (int r = 0; r < 4; ++r) red_sum[rbase + r][wave] = rsum[r];
  __syncthreads();
  float inv[4];
#pragma unroll
  for (int r = 0; r < 4; ++r) {
    float s = red_sum[rbase + r][0] + red_sum[rbase + r][1] +
              red_sum[rbase + r][2] + red_sum[rbase + r][3];
    inv[r] = (s > 0.f) ? (1.f / s) : 0.f;
  }

#pragma unroll
  for (int f = 0; f < 8; ++f) {
#pragma unroll
    for (int r = 0; r < 4; ++r) {
      int i = m0 + rbase + r;
      int k = n0w + f * 16 + col0;
      float d = (dagT[(size_t)i * Tn + k] != 0) ? 1.f : 0.f;
      float p = vals[f][r] * inv[r] + d;   // probs + dagT (fused Vprime)
      P2[((size_t)b * Tn + i) * Tn + k] = f2bf(p);
    }
  }
}

// ---------- stage 4: O = P2 @ V ----------
// grid (T/64, B). A = P2[b] [T,T], B = VT[b] (n=h, k=t contiguous). fp32 out.
__global__ __launch_bounds__(256) void out_kernel(
    const u16* __restrict__ P2, const u16* __restrict__ VT,
    float* __restrict__ O) {
  int b = blockIdx.y;
  int wave = threadIdx.x >> 6, lane = threadIdx.x & 63;
  int mw = blockIdx.x * 64 + wave * 16;
  const u16* Vb = VT + (size_t)b * Hn * Tn;

  f32x4 acc[8] = {};
  const u16* Arow = P2 + ((size_t)b * Tn + mw + (lane & 15)) * Tn + ((lane >> 4) * 8);
  for (int kk = 0; kk < Tn; kk += 32) {
    bf16x8 a = *(const bf16x8*)(Arow + kk);
#pragma unroll
    for (int f = 0; f < 8; ++f) {
      bf16x8 bb = *(const bf16x8*)(Vb + (size_t)(f * 16 + (lane & 15)) * Tn +
                                   ((lane >> 4) * 8) + kk);
      acc[f] = __builtin_amdgcn_mfma_f32_16x16x32_bf16(a, bb, acc[f], 0, 0, 0);
    }
  }
  int col0 = lane & 15, rbase = (lane >> 4) * 4;
#pragma unroll
  for (int f = 0; f < 8; ++f) {
    int h = f * 16 + col0;
#pragma unroll
    for (int r = 0; r < 4; ++r) {
      int i = mw + rbase + r;
      O[((size_t)b * Tn + i) * Hn + h] = acc[f][r];
    }
  }
}

extern "C" void kernel_launch(void* const* d_in, const int* in_sizes, int n_in,
                              void* d_out, int out_size, void* d_ws, size_t ws_size,
                              hipStream_t stream) {
  const float* X   = (const float*)d_in[0];
  const float* dag = (const float*)d_in[1];
  const float* Wk  = (const float*)d_in[2];
  const float* bk  = (const float*)d_in[3];
  const float* Wq  = (const float*)d_in[4];
  const float* bq  = (const float*)d_in[5];
  const float* Wv  = (const float*)d_in[6];
  const float* bv  = (const float*)d_in[7];
  float* O = (float*)d_out;

  char* ws = (char*)d_ws;
  // layout (bytes):
  //   Xb   @ 0          : BT*D*2  = 33,554,432   (aliased by P2 later)
  //   Wb   @ 33,554,432 : 3*H*D*2 =    393,216
  //   dagT @ 33,947,648 : T*T*2   =    524,288
  //   Kb   @ 34,471,936 : B*T*H*2 =  8,388,608
  //   QT   @ 42,860,544 : 8,388,608
  //   VT   @ 51,249,152 : 8,388,608
  //   Q2   @ 59,637,760 : 8,388,608
  u16* Xb   = (u16*)(ws);
  u16* P2   = Xb;  // alias: Xb dead after qkv_kernel
  u16* Wb   = (u16*)(ws + 33554432);
  u16* dagT = (u16*)(ws + 33947648);
  u16* Kb   = (u16*)(ws + 34471936);
  u16* QT   = (u16*)(ws + 42860544);
  u16* VT   = (u16*)(ws + 51249152);
  u16* Q2   = (u16*)(ws + 59637760);

  conv_x<<<(BT * Dn / 4) / 256, 256, 0, stream>>>((const float4*)X, (ushort4*)Xb);
  conv_w<<<(Hn * Dn) / 256, 256, 0, stream>>>(Wk, Wb);
  conv_w<<<(Hn * Dn) / 256, 256, 0, stream>>>(Wq, Wb + Hn * Dn);
  conv_w<<<(Hn * Dn) / 256, 256, 0, stream>>>(Wv, Wb + 2 * Hn * Dn);
  conv_dag<<<(Tn * Tn) / 256, 256, 0, stream>>>(dag, dagT);

  qkv_kernel<<<dim3(BT / 64, 3), 256, 0, stream>>>(Xb, Wb, bk, bq, bv, Kb, QT, VT);
  dagq_kernel<<<dim3(Tn / 64, Bn), 256, 0, stream>>>(dagT, QT, Q2);
  attn_kernel<<<dim3(Tn / 16, Bn), 256, 0, stream>>>(Q2, Kb, dagT, P2);
  out_kernel<<<dim3(Tn / 64, Bn), 256, 0, stream>>>(P2, VT, O);
}

// Round 2
// 120.168 us; speedup vs baseline: 2.0515x; 2.0515x over previous
//
#include <hip/hip_runtime.h>
#include <hip/hip_bf16.h>

#define Bn 64
#define Tn 512
#define Dn 512
#define Hn 128
#define BT (Bn*Tn)

typedef unsigned short u16;
typedef unsigned long long u64;
typedef __attribute__((ext_vector_type(8))) short bf16x8;
typedef __attribute__((ext_vector_type(4))) float f32x4;

__device__ __forceinline__ u16 f2bf(float f) {
  union { float f; unsigned u; } v; v.f = f;
  unsigned r = (v.u + 0x7FFFu + ((v.u >> 16) & 1u)) >> 16;
  return (u16)r;
}

// async global->LDS, 16B per lane; LDS dest = wave-uniform base + lane*16
__device__ __forceinline__ void gload16(const void* g, void* lds) {
  __builtin_amdgcn_global_load_lds(
      (const __attribute__((address_space(1))) unsigned int*)g,
      (__attribute__((address_space(3))) unsigned int*)lds, 16, 0, 0);
}

// ---------- conversions ----------
__global__ __launch_bounds__(256) void conv_f2b(const float4* __restrict__ in,
                                                ushort4* __restrict__ out) {
  int idx = blockIdx.x * 256 + threadIdx.x;
  float4 v = in[idx];
  ushort4 o; o.x = f2bf(v.x); o.y = f2bf(v.y); o.z = f2bf(v.z); o.w = f2bf(v.w);
  out[idx] = o;
}

// coalesced LDS-tiled transpose: dagT[i*T+k] = bf16(dag[k*T+i])
__global__ __launch_bounds__(256) void dag_tr(const float* __restrict__ dag,
                                              u16* __restrict__ dagT) {
  __shared__ float s[64][65];
  int bx = blockIdx.x & 7, by = blockIdx.x >> 3;
  int r0 = by * 64, c0 = bx * 64;          // dag rows r, cols c
  int t = threadIdx.x;
  int c4 = t & 15, rr = t >> 4;            // 16 float4-cols x 16 rows
#pragma unroll
  for (int q = 0; q < 4; ++q) {
    int r = rr + q * 16;
    float4 v = *(const float4*)&dag[(size_t)(r0 + r) * Tn + c0 + c4 * 4];
    s[c4 * 4 + 0][r] = v.x; s[c4 * 4 + 1][r] = v.y;
    s[c4 * 4 + 2][r] = v.z; s[c4 * 4 + 3][r] = v.w;
  }
  __syncthreads();
#pragma unroll
  for (int q = 0; q < 4; ++q) {
    int il = rr + q * 16;                  // i-local (= dag col)
    ushort4 o;
    o.x = f2bf(s[il][c4 * 4 + 0]); o.y = f2bf(s[il][c4 * 4 + 1]);
    o.z = f2bf(s[il][c4 * 4 + 2]); o.w = f2bf(s[il][c4 * 4 + 3]);
    *(ushort4*)&dagT[(size_t)(c0 + il) * Tn + r0 + c4 * 4] = o;
  }
}

// bitmask: bits[i*8+w] bit j = (dagT[i*T + w*64 + j] != 0)
__global__ __launch_bounds__(256) void dag_bits(const u16* __restrict__ dagT,
                                                u64* __restrict__ bits) {
  int idx = blockIdx.x * 256 + threadIdx.x;   // 4096
  int i = idx >> 3, w = idx & 7;
  const u16* p = dagT + (size_t)i * Tn + w * 64;
  u64 m = 0;
#pragma unroll
  for (int j = 0; j < 64; ++j) m |= (u64)(p[j] != 0) << j;
  bits[idx] = m;
}

// ---------- shared 128x128-tile GEMM core (BK=64, m97 structure) ----------
// A: [*, lda] row-major (rows = out rows), B: [*, ldb] row-major (rows = out cols)
__device__ __forceinline__ void gemm_core(const u16* __restrict__ A0, int lda,
                                          const u16* __restrict__ B0, int ldb,
                                          int K, u16* sm, f32x4 (&acc)[4][4]) {
  const int tid = threadIdx.x;
  const int lane = tid & 63, wave = tid >> 6;
  const int wr = wave >> 1, wc = wave & 1;
  const int kcb = (lane >> 4) * 16;            // byte offset of 8-elem k-chunk
  const int arow = wr * 64 + (lane & 15);
  const int brow = wc * 64 + (lane & 15);
  const char* Ab = (const char*)A0;
  const char* Bb = (const char*)B0;
  char* smb = (char*)sm;

  for (int kt = 0; kt < K; kt += 64) {
#pragma unroll
    for (int q = 0; q < 4; ++q) {
      int flat = wave * 4096 + q * 1024 + lane * 16;
      int row = flat >> 7, colb = flat & 127;
      gload16(Ab + (size_t)row * (lda * 2) + kt * 2 + colb,
              smb + wave * 4096 + q * 1024);
      gload16(Bb + (size_t)row * (ldb * 2) + kt * 2 + colb,
              smb + 16384 + wave * 4096 + q * 1024);
    }
    __syncthreads();
    bf16x8 af[4][2], bf[4][2];
#pragma unroll
    for (int m = 0; m < 4; ++m)
#pragma unroll
      for (int kk = 0; kk < 2; ++kk) {
        af[m][kk] = *(const bf16x8*)(smb + (arow + m * 16) * 128 + kk * 64 + kcb);
        bf[m][kk] = *(const bf16x8*)(smb + 16384 + (brow + m * 16) * 128 + kk * 64 + kcb);
      }
#pragma unroll
    for (int kk = 0; kk < 2; ++kk)
#pragma unroll
      for (int m = 0; m < 4; ++m)
#pragma unroll
        for (int n = 0; n < 4; ++n)
          acc[m][n] = __builtin_amdgcn_mfma_f32_16x16x32_bf16(af[m][kk], bf[n][kk],
                                                              acc[m][n], 0, 0, 0);
    __syncthreads();
  }
}

// ---------- stage 1: K,Q,V = swish(X W^T + b) ----------
// grid (BT/128, 3); which = blockIdx.y. K row-major [BT,H]; Q,V -> [B,H,T].
__global__ __launch_bounds__(256) void qkv_tiled(
    const u16* __restrict__ Xb, const u16* __restrict__ Wcat,
    const float* __restrict__ bk, const float* __restrict__ bq,
    const float* __restrict__ bv,
    u16* __restrict__ Kb, u16* __restrict__ QT, u16* __restrict__ VT) {
  __shared__ u16 sm[16384];
  int which = blockIdx.y;
  int m0 = blockIdx.x * 128;
  f32x4 acc[4][4] = {};
  gemm_core(Xb + (size_t)m0 * Dn, Dn, Wcat + (size_t)which * 128 * Dn, Dn, Dn, sm, acc);

  int lane = threadIdx.x & 63, wave = threadIdx.x >> 6;
  int wr = wave >> 1, wc = wave & 1;
  int col0 = lane & 15, rg = lane >> 4;
  const float* bias = (which == 0) ? bk : (which == 1) ? bq : bv;
  if (which == 0) {
#pragma unroll
    for (int n = 0; n < 4; ++n) {
      int nl = wc * 64 + n * 16 + col0;
      float bs = bias[nl];
#pragma unroll
      for (int m = 0; m < 4; ++m)
#pragma unroll
        for (int r = 0; r < 4; ++r) {
          int t = m0 + wr * 64 + m * 16 + rg * 4 + r;
          float x = acc[m][n][r] + bs;
          Kb[(size_t)t * Hn + nl] = f2bf(x / (1.f + __expf(-x)));
        }
    }
  } else {
    u16* dst = (which == 1) ? QT : VT;
#pragma unroll
    for (int n = 0; n < 4; ++n) {
      int nl = wc * 64 + n * 16 + col0;
      float bs = bias[nl];
#pragma unroll
      for (int m = 0; m < 4; ++m) {
        int t0 = m0 + wr * 64 + m * 16 + rg * 4;
        int bb = t0 >> 9, tt = t0 & (Tn - 1);
        ushort4 o;
#pragma unroll
        for (int r = 0; r < 4; ++r) {
          float x = acc[m][n][r] + bs;
          ((u16*)&o)[r] = f2bf(x / (1.f + __expf(-x)));
        }
        *(ushort4*)&dst[((size_t)bb * Hn + nl) * Tn + tt] = o;
      }
    }
  }
}

// ---------- stage 2: Q2 = (dagT @ Q)/sqrt(H) ----------  grid (4, B)
__global__ __launch_bounds__(256) void dagq_tiled(
    const u16* __restrict__ dagT, const u16* __restrict__ QT,
    u16* __restrict__ Q2) {
  __shared__ u16 sm[16384];
  int b = blockIdx.y, m0 = blockIdx.x * 128;
  f32x4 acc[4][4] = {};
  gemm_core(dagT + (size_t)m0 * Tn, Tn, QT + (size_t)b * Hn * Tn, Tn, Tn, sm, acc);

  const float scale = 0.08838834764831845f;
  int lane = threadIdx.x & 63, wave = threadIdx.x >> 6;
  int wr = wave >> 1, wc = wave & 1;
  int col0 = lane & 15, rg = lane >> 4;
#pragma unroll
  for (int n = 0; n < 4; ++n) {
    int h = wc * 64 + n * 16 + col0;
#pragma unroll
    for (int m = 0; m < 4; ++m)
#pragma unroll
      for (int r = 0; r < 4; ++r) {
        int i = m0 + wr * 64 + m * 16 + rg * 4 + r;
        Q2[((size_t)b * Tn + i) * Hn + h] = f2bf(acc[m][n][r] * scale);
      }
  }
}

// ---------- stage 3: fused S=Q2 K^T, DAG mask, softmax, P2 = probs + dagT ----------
// grid (4, B), 512 threads (8 waves: wr in {0,1}, wc in {0..3}); block = 128 rows x 512 cols.
__global__ __launch_bounds__(512, 2) void attn_fused(
    const u16* __restrict__ Q2, const u16* __restrict__ Kb,
    const u64* __restrict__ dbits, u16* __restrict__ P2) {
  __shared__ u16 smQ[128 * 128];     // 32KB Q2 tile
  __shared__ u64 smB[128 * 8];       // 8KB mask bits
  __shared__ float red_max[128][4];
  __shared__ float red_sum[128][4];

  int b = blockIdx.y, m0 = blockIdx.x * 128;
  int tid = threadIdx.x, lane = tid & 63, wave = tid >> 6;
  int wr = wave >> 2, wc = wave & 3;
  int col0 = lane & 15, rg = lane >> 4;
  const int kcb = rg * 16;

  // stage Q2 tile (128 rows x 128 h = 32KB): 4 issues x 8 waves x 1KB
  const char* A0 = (const char*)(Q2 + ((size_t)b * Tn + m0) * Hn);
#pragma unroll
  for (int q = 0; q < 4; ++q) {
    int chunk = q * 8 + wave;                 // 0..31, 1KB each
    int flat = chunk * 1024 + lane * 16;
    int row = flat >> 8, colb = flat & 255;
    gload16(A0 + (size_t)row * 256 + colb, (char*)smQ + chunk * 1024);
  }
  // stage mask bits (128 rows x 64B = 8KB): 1 issue
  gload16((const char*)dbits + (size_t)m0 * 64 + wave * 1024 + lane * 16,
          (char*)smB + wave * 1024);
  __syncthreads();

  // S = Q2 K^T : acc[m][nf] covers rows wr*64+m*16.., cols wc*128+nf*16..
  f32x4 acc[4][8] = {};
  const char* Kbase = (const char*)(Kb + (size_t)b * Tn * Hn);
#pragma unroll
  for (int kk = 0; kk < 4; ++kk) {
    bf16x8 af[4], bf[8];
#pragma unroll
    for (int m = 0; m < 4; ++m)
      af[m] = *(const bf16x8*)((char*)smQ + (wr * 64 + m * 16 + col0) * 256 + kk * 64 + kcb);
#pragma unroll
    for (int nf = 0; nf < 8; ++nf)
      bf[nf] = *(const bf16x8*)(Kbase + (size_t)(wc * 128 + nf * 16 + col0) * 256 + kk * 64 + kcb);
#pragma unroll
    for (int m = 0; m < 4; ++m)
#pragma unroll
      for (int nf = 0; nf < 8; ++nf)
        acc[m][nf] = __builtin_amdgcn_mfma_f32_16x16x32_bf16(af[m], bf[nf], acc[m][nf], 0, 0, 0);
  }

  // mask + row max
  float rmax[4][4];
#pragma unroll
  for (int m = 0; m < 4; ++m)
#pragma unroll
    for (int r = 0; r < 4; ++r) {
      int rl = wr * 64 + m * 16 + rg * 4 + r;
      u64 w0 = smB[rl * 8 + wc * 2 + 0];
      u64 w1 = smB[rl * 8 + wc * 2 + 1];
      float mx = -INFINITY;
#pragma unroll
      for (int nf = 0; nf < 8; ++nf) {
        u64 w = (nf < 4) ? w0 : w1;
        int bp = (nf & 3) * 16 + col0;
        float v = ((w >> bp) & 1) ? acc[m][nf][r] : -INFINITY;
        acc[m][nf][r] = v;
        mx = fmaxf(mx, v);
      }
      rmax[m][r] = mx;
    }
#pragma unroll
  for (int s = 1; s < 16; s <<= 1)
#pragma unroll
    for (int m = 0; m < 4; ++m)
#pragma unroll
      for (int r = 0; r < 4; ++r)
        rmax[m][r] = fmaxf(rmax[m][r], __shfl_xor(rmax[m][r], s, 64));
  if (col0 == 0)
#pragma unroll
    for (int m = 0; m < 4; ++m)
#pragma unroll
      for (int r = 0; r < 4; ++r)
        red_max[wr * 64 + m * 16 + rg * 4 + r][wc] = rmax[m][r];
  __syncthreads();

  // exp + row sum
  float rsum[4][4];
#pragma unroll
  for (int m = 0; m < 4; ++m)
#pragma unroll
    for (int r = 0; r < 4; ++r) {
      int rl = wr * 64 + m * 16 + rg * 4 + r;
      float mm = fmaxf(fmaxf(red_max[rl][0], red_max[rl][1]),
                       fmaxf(red_max[rl][2], red_max[rl][3]));
      float rowmax = (mm == -INFINITY) ? 0.f : mm;
      float s = 0.f;
#pragma unroll
      for (int nf = 0; nf < 8; ++nf) {
        float v = acc[m][nf][r];
        float e = (v == -INFINITY) ? 0.f : __expf(v - rowmax);
        acc[m][nf][r] = e;
        s += e;
      }
      rsum[m][r] = s;
    }
#pragma unroll
  for (int s = 1; s < 16; s <<= 1)
#pragma unroll
    for (int m = 0; m < 4; ++m)
#pragma unroll
      for (int r = 0; r < 4; ++r)
        rsum[m][r] += __shfl_xor(rsum[m][r], s, 64);
  if (col0 == 0)
#pragma unroll
    for (int m = 0; m < 4; ++m)
#pragma unroll
      for (int r = 0; r < 4; ++r)
        red_sum[wr * 64 + m * 16 + rg * 4 + r][wc] = rsum[m][r];
  __syncthreads();

  // normalize + add dagT + store
#pragma unroll
  for (int m = 0; m < 4; ++m)
#pragma unroll
    for (int r = 0; r < 4; ++r) {
      int rl = wr * 64 + m * 16 + rg * 4 + r;
      float s = red_sum[rl][0] + red_sum[rl][1] + red_sum[rl][2] + red_sum[rl][3];
      float inv = (s > 0.f) ? (1.f / s) : 0.f;
      u64 w0 = smB[rl * 8 + wc * 2 + 0];
      u64 w1 = smB[rl * 8 + wc * 2 + 1];
      int i = m0 + rl;
#pragma unroll
      for (int nf = 0; nf < 8; ++nf) {
        u64 w = (nf < 4) ? w0 : w1;
        int bp = (nf & 3) * 16 + col0;
        float d = (float)((w >> bp) & 1);
        float p = acc[m][nf][r] * inv + d;
        P2[((size_t)b * Tn + i) * Tn + wc * 128 + nf * 16 + col0] = f2bf(p);
      }
    }
}

// ---------- stage 4: O = P2 @ V ----------  grid (4, B)
__global__ __launch_bounds__(256) void out_tiled(
    const u16* __restrict__ P2, const u16* __restrict__ VT,
    float* __restrict__ O) {
  __shared__ u16 sm[16384];
  int b = blockIdx.y, m0 = blockIdx.x * 128;
  f32x4 acc[4][4] = {};
  gemm_core(P2 + ((size_t)b * Tn + m0) * Tn, Tn, VT + (size_t)b * Hn * Tn, Tn, Tn, sm, acc);

  int lane = threadIdx.x & 63, wave = threadIdx.x >> 6;
  int wr = wave >> 1, wc = wave & 1;
  int col0 = lane & 15, rg = lane >> 4;
#pragma unroll
  for (int n = 0; n < 4; ++n) {
    int h = wc * 64 + n * 16 + col0;
#pragma unroll
    for (int m = 0; m < 4; ++m)
#pragma unroll
      for (int r = 0; r < 4; ++r) {
        int i = m0 + wr * 64 + m * 16 + rg * 4 + r;
        O[((size_t)b * Tn + i) * Hn + h] = acc[m][n][r];
      }
  }
}

extern "C" void kernel_launch(void* const* d_in, const int* in_sizes, int n_in,
                              void* d_out, int out_size, void* d_ws, size_t ws_size,
                              hipStream_t stream) {
  const float* X   = (const float*)d_in[0];
  const float* dag = (const float*)d_in[1];
  const float* Wk  = (const float*)d_in[2];
  const float* bk  = (const float*)d_in[3];
  const float* Wq  = (const float*)d_in[4];
  const float* bq  = (const float*)d_in[5];
  const float* Wv  = (const float*)d_in[6];
  const float* bv  = (const float*)d_in[7];
  float* O = (float*)d_out;

  char* ws = (char*)d_ws;
  u16* Xb   = (u16*)(ws);                 // 33,554,432 B (aliased by P2)
  u16* P2   = Xb;
  u16* Wcat = (u16*)(ws + 33554432);      //    393,216
  u16* dagT = (u16*)(ws + 33947648);      //    524,288
  u64* dbits= (u64*)(ws + 34471936);      //     32,768
  u16* Kb   = (u16*)(ws + 34504704);      //  8,388,608
  u16* QT   = (u16*)(ws + 42893312);      //  8,388,608
  u16* VT   = (u16*)(ws + 51281920);      //  8,388,608
  u16* Q2   = (u16*)(ws + 59670528);      //  8,388,608  (end 68,059,136)

  conv_f2b<<<(BT * Dn / 4) / 256, 256, 0, stream>>>((const float4*)X, (ushort4*)Xb);
  conv_f2b<<<(Hn * Dn / 4) / 256, 256, 0, stream>>>((const float4*)Wk, (ushort4*)Wcat);
  conv_f2b<<<(Hn * Dn / 4) / 256, 256, 0, stream>>>((const float4*)Wq, (ushort4*)(Wcat + Hn * Dn));
  conv_f2b<<<(Hn * Dn / 4) / 256, 256, 0, stream>>>((const float4*)Wv, (ushort4*)(Wcat + 2 * Hn * Dn));
  dag_tr<<<64, 256, 0, stream>>>(dag, dagT);
  dag_bits<<<16, 256, 0, stream>>>(dagT, dbits);

  qkv_tiled<<<dim3(BT / 128, 3), 256, 0, stream>>>(Xb, Wcat, bk, bq, bv, Kb, QT, VT);
  dagq_tiled<<<dim3(Tn / 128, Bn), 256, 0, stream>>>(dagT, QT, Q2);
  attn_fused<<<dim3(Tn / 128, Bn), 512, 0, stream>>>(Q2, Kb, dbits, P2);
  out_tiled<<<dim3(Tn / 128, Bn), 256, 0, stream>>>(P2, VT, O);
}